// Round 1
// baseline (114.922 us; speedup 1.0000x reference)
//
#include <hip/hip_runtime.h>

// Problem constants (from reference setup_inputs)
static constexpr int B_ = 2, N_ = 2048, NL_ = 512, IN_C_ = 16, C_ = 32, H_ = 32;
static constexpr float R1SQ = (float)(0.07 * 0.07);   // (RADIUS*1)^2, double->f32 like numpy
static constexpr float R2SQ = (float)(0.14 * 0.14);   // (RADIUS*2)^2

// jax.nn.gelu(approximate=True): 0.5x(1+tanh(sqrt(2/pi)(x+0.044715x^3)))
// identity: 0.5x(1+tanh(z)) = x * (1 - 1/(exp(2z)+1))   (safe at +/-inf)
__device__ __forceinline__ float gelu_tanh(float x) {
    float z2 = 2.0f * 0.7978845608028654f * x * fmaf(0.044715f * x, x, 1.0f);
    float e = __expf(z2);
    return x * (1.0f - 1.0f / (e + 1.0f));
}

// f = pndata @ W_lift + b_lift   (B*N rows of 16 -> 32)
__global__ __launch_bounds__(256)
void lift_kernel(const float* __restrict__ pnd,
                 const float* __restrict__ Wl, const float* __restrict__ bl,
                 float* __restrict__ f)
{
    __shared__ float sW[IN_C_ * C_];   // [m][c]
    __shared__ float sb[C_];
    int tid = threadIdx.x;
    for (int idx = tid; idx < IN_C_ * C_; idx += 256) sW[idx] = Wl[idx];
    if (tid < C_) sb[tid] = bl[tid];
    __syncthreads();
    int c = tid & 31;
    int row = blockIdx.x * 8 + (tid >> 5);
    if (row >= B_ * N_) return;
    const float* p = pnd + (size_t)row * IN_C_;
    float s = sb[c];
#pragma unroll
    for (int m = 0; m < IN_C_; ++m) s = fmaf(p[m], sW[m * C_ + c], s);
    f[(size_t)row * C_ + c] = s;   // coalesced: 32 consecutive channels per row-group
}

// One block per (b, latent token i). 128 threads.
template<bool USE_F>
__global__ __launch_bounds__(128)
void magno_main(const float* __restrict__ x_coord,   // (B,N,2)
                const float* __restrict__ lat,        // (NL,2)
                const float* __restrict__ kW1, const float* __restrict__ kb1,
                const float* __restrict__ kW2, const float* __restrict__ kb2,
                const float* __restrict__ kW3, const float* __restrict__ kb3,
                const float* __restrict__ f,          // (B,N,32) or null
                const float* __restrict__ pnd,        // (B,N,16) fallback path
                const float* __restrict__ Wl, const float* __restrict__ bl,
                float* __restrict__ out)              // (B,NL,32)
{
    __shared__ float sW2T[H_ * H_];    // transposed: [k][m] contiguous in m
    __shared__ float sW3T[C_ * H_];    // transposed: [c][m]
    __shared__ float sR0[H_], sR1[H_], sA1[H_], sB2[H_], sB3[C_];
    __shared__ float sWlT[C_ * IN_C_]; // [c][m] (fallback only)
    __shared__ float sbl[C_];
    __shared__ unsigned jlist[N_];
    __shared__ int s_n, s_c1;
    __shared__ float wred[2][C_];

    const int tid = threadIdx.x;
    const int bi = blockIdx.x;
    const int b = bi / NL_, i = bi % NL_;
    const float xq0 = lat[2 * i], xq1 = lat[2 * i + 1];

    for (int idx = tid; idx < H_ * H_; idx += 128) {
        int m = idx >> 5, k = idx & 31;
        sW2T[k * H_ + m] = kW2[idx];
        sW3T[k * H_ + m] = kW3[idx];
    }
    if (tid < H_) {
        sR0[tid] = kW1[tid];            // W1 row 0 (y0)
        sR1[tid] = kW1[H_ + tid];       // W1 row 1 (y1)
        // fold xq-dependent part + bias: A1[k] = xq0*W1[2][k] + xq1*W1[3][k] + b1[k]
        sA1[tid] = fmaf(xq0, kW1[2 * H_ + tid], fmaf(xq1, kW1[3 * H_ + tid], kb1[tid]));
        sB2[tid] = kb2[tid];
        sB3[tid] = kb3[tid];
    }
    if (!USE_F) {
        for (int idx = tid; idx < IN_C_ * C_; idx += 128) {
            int m = idx >> 5, c = idx & 31;
            sWlT[c * IN_C_ + m] = Wl[idx];
        }
        if (tid < C_) sbl[tid] = bl[tid];
    }
    if (tid == 0) { s_n = 0; s_c1 = 0; }
    __syncthreads();

    // ---- Pass A: compact qualifying neighbor list + counts ----
    const float2* __restrict__ xc = (const float2*)(x_coord + (size_t)b * N_ * 2);
    for (int j = tid; j < N_; j += 128) {
        float2 y = xc[j];
        float dy0 = y.x - xq0, dy1 = y.y - xq1;
        float d2 = dy0 * dy0 + dy1 * dy1;
        if (d2 <= R2SQ) {
            int pos = atomicAdd(&s_n, 1);
            bool inner = (d2 <= R1SQ);
            jlist[pos] = (unsigned)j | (inner ? 0x80000000u : 0u);
            if (inner) atomicAdd(&s_c1, 1);
        }
    }
    __syncthreads();
    const int n = s_n;
    const float inv2 = 1.0f / (float)(n > 0 ? n : 1);
    const float inv1 = 1.0f / (float)(s_c1 > 0 ? s_c1 : 1);

    float acc[C_];
#pragma unroll
    for (int c = 0; c < C_; ++c) acc[c] = 0.0f;

    // ---- Pass B: MLP only on qualifying entries ----
    for (int e = tid; e < n; e += 128) {
        unsigned packed = jlist[e];
        int j = (int)(packed & 0x7fffffffu);
        float w = inv2 + ((packed & 0x80000000u) ? inv1 : 0.0f);
        float2 y = xc[j];

        float h1[H_];
#pragma unroll
        for (int k = 0; k < H_; ++k)
            h1[k] = gelu_tanh(fmaf(y.x, sR0[k], fmaf(y.y, sR1[k], sA1[k])));

        float h2[H_];
#pragma unroll 4
        for (int k = 0; k < H_; ++k) {
            const float4* w4 = (const float4*)(sW2T + k * H_);
            float s = sB2[k];
#pragma unroll
            for (int q = 0; q < 8; ++q) {
                float4 wv = w4[q];   // uniform address -> LDS broadcast, no conflict
                s = fmaf(h1[4 * q + 0], wv.x, s);
                s = fmaf(h1[4 * q + 1], wv.y, s);
                s = fmaf(h1[4 * q + 2], wv.z, s);
                s = fmaf(h1[4 * q + 3], wv.w, s);
            }
            h2[k] = gelu_tanh(s);
        }

        float fj[C_];
        if (USE_F) {
            const float4* f4 = (const float4*)(f + ((size_t)b * N_ + j) * C_);
#pragma unroll
            for (int q = 0; q < 8; ++q) {
                float4 v = f4[q];
                fj[4 * q + 0] = v.x; fj[4 * q + 1] = v.y;
                fj[4 * q + 2] = v.z; fj[4 * q + 3] = v.w;
            }
        } else {
            float in[IN_C_];
            const float4* p4 = (const float4*)(pnd + ((size_t)b * N_ + j) * IN_C_);
#pragma unroll
            for (int q = 0; q < 4; ++q) {
                float4 v = p4[q];
                in[4 * q + 0] = v.x; in[4 * q + 1] = v.y;
                in[4 * q + 2] = v.z; in[4 * q + 3] = v.w;
            }
#pragma unroll
            for (int c = 0; c < C_; ++c) {
                float s = sbl[c];
#pragma unroll
                for (int m = 0; m < IN_C_; ++m) s = fmaf(in[m], sWlT[c * IN_C_ + m], s);
                fj[c] = s;
            }
        }

#pragma unroll 4
        for (int c = 0; c < C_; ++c) {
            const float4* w4 = (const float4*)(sW3T + c * H_);
            float s = sB3[c];
#pragma unroll
            for (int q = 0; q < 8; ++q) {
                float4 wv = w4[q];
                s = fmaf(h2[4 * q + 0], wv.x, s);
                s = fmaf(h2[4 * q + 1], wv.y, s);
                s = fmaf(h2[4 * q + 2], wv.z, s);
                s = fmaf(h2[4 * q + 3], wv.w, s);
            }
            acc[c] = fmaf(w * fj[c], s, acc[c]);   // kv[c] * f[j][c] * weight
        }
    }

    // ---- Reduce acc across the block ----
#pragma unroll
    for (int c = 0; c < C_; ++c) {
        float v = acc[c];
#pragma unroll
        for (int off = 1; off < 64; off <<= 1)
            v += __shfl_xor(v, off, 64);
        acc[c] = v;
    }
    const int wid = tid >> 6;
    if ((tid & 63) == 0) {
#pragma unroll
        for (int c = 0; c < C_; ++c) wred[wid][c] = acc[c];
    }
    __syncthreads();
    if (tid < C_) {
        out[(size_t)bi * C_ + tid] = wred[0][tid] + wred[1][tid];
    }
}

extern "C" void kernel_launch(void* const* d_in, const int* in_sizes, int n_in,
                              void* d_out, int out_size, void* d_ws, size_t ws_size,
                              hipStream_t stream) {
    const float* x_coord = (const float*)d_in[0];
    const float* pndata  = (const float*)d_in[1];
    const float* lat     = (const float*)d_in[2];
    const float* W_lift  = (const float*)d_in[3];
    const float* b_lift  = (const float*)d_in[4];
    const float* kW1     = (const float*)d_in[5];
    const float* kb1     = (const float*)d_in[6];
    const float* kW2     = (const float*)d_in[7];
    const float* kb2     = (const float*)d_in[8];
    const float* kW3     = (const float*)d_in[9];
    const float* kb3     = (const float*)d_in[10];
    float* out = (float*)d_out;

    const size_t f_bytes = (size_t)B_ * N_ * C_ * sizeof(float);
    if (ws_size >= f_bytes) {
        float* f = (float*)d_ws;
        lift_kernel<<<(B_ * N_ + 7) / 8, 256, 0, stream>>>(pndata, W_lift, b_lift, f);
        magno_main<true><<<B_ * NL_, 128, 0, stream>>>(
            x_coord, lat, kW1, kb1, kW2, kb2, kW3, kb3,
            f, pndata, W_lift, b_lift, out);
    } else {
        magno_main<false><<<B_ * NL_, 128, 0, stream>>>(
            x_coord, lat, kW1, kb1, kW2, kb2, kW3, kb3,
            nullptr, pndata, W_lift, b_lift, out);
    }
}

// Round 2
// 97.110 us; speedup vs baseline: 1.1834x; 1.1834x over previous
//
#include <hip/hip_runtime.h>

// Problem constants (from reference setup_inputs)
static constexpr int B_ = 2, N_ = 2048, NL_ = 512, IN_C_ = 16, C_ = 32, H_ = 32;
static constexpr float R1SQ = (float)(0.07 * 0.07);   // (RADIUS*1)^2, double->f32 like numpy
static constexpr float R2SQ = (float)(0.14 * 0.14);   // (RADIUS*2)^2

typedef __attribute__((ext_vector_type(8))) short bf16x8;  // 8 bf16 = 4 VGPRs
typedef __attribute__((ext_vector_type(4))) float f32x4;   // 4 fp32 acc

// jax.nn.gelu(approximate=True): 0.5x(1+tanh(sqrt(2/pi)(x+0.044715x^3)))
// identity: 0.5x(1+tanh(z)) = x * (1 - 1/(exp(2z)+1))   (safe at +/-inf)
__device__ __forceinline__ float gelu_tanh(float x) {
    float z2 = 2.0f * 0.7978845608028654f * x * fmaf(0.044715f * x, x, 1.0f);
    float e = __expf(z2);
    return x * (1.0f - 1.0f / (e + 1.0f));
}

// fp32 -> bf16 bits, round-to-nearest-even (inputs are finite; no NaN handling)
__device__ __forceinline__ short f2bf(float x) {
    unsigned u = __float_as_uint(x);
    u += 0x7fffu + ((u >> 16) & 1u);
    return (short)(u >> 16);
}

// f = pndata @ W_lift + b_lift   (B*N rows of 16 -> 32)
__global__ __launch_bounds__(256)
void lift_kernel(const float* __restrict__ pnd,
                 const float* __restrict__ Wl, const float* __restrict__ bl,
                 float* __restrict__ f)
{
    __shared__ float sW[IN_C_ * C_];   // [m][c]
    __shared__ float sb[C_];
    int tid = threadIdx.x;
    for (int idx = tid; idx < IN_C_ * C_; idx += 256) sW[idx] = Wl[idx];
    if (tid < C_) sb[tid] = bl[tid];
    __syncthreads();
    int c = tid & 31;
    int row = blockIdx.x * 8 + (tid >> 5);
    if (row >= B_ * N_) return;
    const float* p = pnd + (size_t)row * IN_C_;
    float s = sb[c];
#pragma unroll
    for (int m = 0; m < IN_C_; ++m) s = fmaf(p[m], sW[m * C_ + c], s);
    f[(size_t)row * C_ + c] = s;
}

// One block per (b, latent token i). 128 threads = 2 waves.
// Each wave processes chunks of 64 entries via mfma_f32_16x16x32_bf16:
//   4 M-tiles (16 entries) x 2 N-tiles (16 neurons), K=32 in one mfma.
__global__ __launch_bounds__(128)
void magno_mfma(const float* __restrict__ x_coord,   // (B,N,2)
                const float* __restrict__ lat,        // (NL,2)
                const float* __restrict__ kW1, const float* __restrict__ kb1,
                const float* __restrict__ kW2, const float* __restrict__ kb2,
                const float* __restrict__ kW3, const float* __restrict__ kb3,
                const float* __restrict__ f,          // (B,N,32)
                float* __restrict__ out)              // (B,NL,32)
{
    __shared__ float sR0[H_], sR1[H_], sA1[H_], sB2[H_], sB3[C_];
    __shared__ unsigned jlist[N_];
    __shared__ float strans[2][64 * 33];   // per-wave transpose buffer (stride 33: bank-conflict-free reads)
    __shared__ float sred[2][C_];
    __shared__ int s_n, s_c1;

    const int tid  = threadIdx.x;
    const int lane = tid & 63;
    const int wid  = tid >> 6;
    const int qd   = lane >> 4;    // quad 0..3
    const int li   = lane & 15;
    const int bi = blockIdx.x;
    const int b = bi >> 9, i = bi & (NL_ - 1);
    const float xq0 = lat[2 * i], xq1 = lat[2 * i + 1];

    if (tid < H_) {
        sR0[tid] = kW1[tid];            // W1 row 0 (y0)
        sR1[tid] = kW1[H_ + tid];       // W1 row 1 (y1)
        // fold xq-dependent part + bias: A1[k] = xq0*W1[2][k] + xq1*W1[3][k] + b1[k]
        sA1[tid] = fmaf(xq0, kW1[2 * H_ + tid], fmaf(xq1, kW1[3 * H_ + tid], kb1[tid]));
        sB2[tid] = kb2[tid];
        sB3[tid] = kb3[tid];
    }
    if (tid == 0) { s_n = 0; s_c1 = 0; }

    // B-fragments for W2, W3 (held in registers whole kernel):
    // B[k=(lane>>4)*8+j][n=(lane&15)+16*nt], row-major weights W[k*32+n]
    bf16x8 w2f[2], w3f[2];
#pragma unroll
    for (int nt = 0; nt < 2; ++nt) {
#pragma unroll
        for (int j = 0; j < 8; ++j) {
            int k = qd * 8 + j;
            int n = li + 16 * nt;
            w2f[nt][j] = f2bf(kW2[k * H_ + n]);
            w3f[nt][j] = f2bf(kW3[k * C_ + n]);
        }
    }
    __syncthreads();

    // ---- Pass A: compact qualifying neighbor list + counts ----
    const float2* __restrict__ xc = (const float2*)(x_coord + (size_t)b * N_ * 2);
    for (int j = tid; j < N_; j += 128) {
        float2 y = xc[j];
        float dy0 = y.x - xq0, dy1 = y.y - xq1;
        float d2 = dy0 * dy0 + dy1 * dy1;   // keep identical to R1 (FMA contraction behavior)
        if (d2 <= R2SQ) {
            int pos = atomicAdd(&s_n, 1);
            bool inner = (d2 <= R1SQ);
            jlist[pos] = (unsigned)j | (inner ? 0x80000000u : 0u);
            if (inner) atomicAdd(&s_c1, 1);
        }
    }
    __syncthreads();
    const int n = s_n;
    const float inv2 = 1.0f / (float)(n > 0 ? n : 1);
    const float inv1 = 1.0f / (float)(s_c1 > 0 ? s_c1 : 1);

    // layer-1 weight slices for this lane's k-range (loop-invariant)
    float r0v[8], r1v[8], a1v[8], b2v[H_];
#pragma unroll
    for (int j = 0; j < 8; ++j) {
        int k = qd * 8 + j;
        r0v[j] = sR0[k]; r1v[j] = sR1[k]; a1v[j] = sA1[k];
    }
    float* tb = &strans[wid][0];
    const float* fbase = f + (size_t)b * N_ * C_;

    float accA = 0.0f, accB = 0.0f;   // channel li and li+16 partial sums
    const int nIter = (n + 127) >> 7;

    for (int it = 0; it < nIter; ++it) {
        const int base = it * 128 + 64 * wid;

        // ---- layer 1, computed directly in A-fragment layout ----
        // lane holds h1[e = base+16*mt+li][k = qd*8+j]
        bf16x8 hfrag[4];
#pragma unroll
        for (int mt = 0; mt < 4; ++mt) {
            int e = base + 16 * mt + li;
            unsigned pk = jlist[e < N_ ? e : 0];   // garbage ok when e>=n (weight 0 later)
            int j = (int)(pk & (unsigned)(N_ - 1));
            float2 y = xc[j];
#pragma unroll
            for (int jj = 0; jj < 8; ++jj) {
                float h = gelu_tanh(fmaf(y.x, r0v[jj], fmaf(y.y, r1v[jj], a1v[jj])));
                hfrag[mt][jj] = f2bf(h);
            }
        }

        // ---- layer 2 mfma: H2 = H1 @ W2 ----
        f32x4 acc2[4][2];
#pragma unroll
        for (int mt = 0; mt < 4; ++mt)
#pragma unroll
            for (int nt = 0; nt < 2; ++nt) {
                f32x4 z = {0.f, 0.f, 0.f, 0.f};
                acc2[mt][nt] = __builtin_amdgcn_mfma_f32_16x16x32_bf16(hfrag[mt], w2f[nt], z, 0, 0, 0);
            }

        // ---- bias + gelu, write C-layout -> LDS (row = entry, col = neuron) ----
        // C/D: col = lane&15 (+16*nt), row-in-tile = qd*4 + reg
#pragma unroll
        for (int mt = 0; mt < 4; ++mt)
#pragma unroll
            for (int nt = 0; nt < 2; ++nt)
#pragma unroll
                for (int r = 0; r < 4; ++r) {
                    int nn = li + 16 * nt;
                    float v = gelu_tanh(acc2[mt][nt][r] + sB2[nn]);
                    int el = 16 * mt + qd * 4 + r;
                    tb[el * 33 + nn] = v;
                }
        __syncthreads();   // drain LDS writes (cross-lane transpose within wave)

        // ---- read back as A-fragment for layer 3 ----
        bf16x8 h2f[4];
#pragma unroll
        for (int mt = 0; mt < 4; ++mt) {
            int row = 16 * mt + li;
#pragma unroll
            for (int jj = 0; jj < 8; ++jj)
                h2f[mt][jj] = f2bf(tb[row * 33 + qd * 8 + jj]);
        }
        __syncthreads();   // protect buffer before next iteration's writes

        // ---- layer 3 mfma: KV = H2 @ W3 ----
        f32x4 acc3[4][2];
#pragma unroll
        for (int mt = 0; mt < 4; ++mt)
#pragma unroll
            for (int nt = 0; nt < 2; ++nt) {
                f32x4 z = {0.f, 0.f, 0.f, 0.f};
                acc3[mt][nt] = __builtin_amdgcn_mfma_f32_16x16x32_bf16(h2f[mt], w3f[nt], z, 0, 0, 0);
            }

        // ---- epilogue: acc_c += w_e * f[j_e][c] * (kv_e[c] + b3[c]) ----
#pragma unroll
        for (int mt = 0; mt < 4; ++mt)
#pragma unroll
            for (int r = 0; r < 4; ++r) {
                int el = 16 * mt + qd * 4 + r;
                int e = base + el;
                unsigned pk = jlist[e < N_ ? e : 0];
                int j = (int)(pk & (unsigned)(N_ - 1));
                float w = (e < n) ? (inv2 + ((pk & 0x80000000u) ? inv1 : 0.0f)) : 0.0f;
                const float* fr = fbase + (size_t)j * C_;
                float fA = fr[li], fB = fr[li + 16];
                float kvA = acc3[mt][0][r] + sB3[li];
                float kvB = acc3[mt][1][r] + sB3[li + 16];
                accA = fmaf(w * fA, kvA, accA);
                accB = fmaf(w * fB, kvB, accB);
            }
    }

    // ---- reduce: entries live on quad groups -> 2 shuffles; channels already on lanes ----
    accA += __shfl_xor(accA, 16, 64);
    accA += __shfl_xor(accA, 32, 64);
    accB += __shfl_xor(accB, 16, 64);
    accB += __shfl_xor(accB, 32, 64);
    if (lane < 16) {
        sred[wid][li] = accA;
        sred[wid][li + 16] = accB;
    }
    __syncthreads();
    if (tid < C_) out[(size_t)bi * C_ + tid] = sred[0][tid] + sred[1][tid];
}

extern "C" void kernel_launch(void* const* d_in, const int* in_sizes, int n_in,
                              void* d_out, int out_size, void* d_ws, size_t ws_size,
                              hipStream_t stream) {
    const float* x_coord = (const float*)d_in[0];
    const float* pndata  = (const float*)d_in[1];
    const float* lat     = (const float*)d_in[2];
    const float* W_lift  = (const float*)d_in[3];
    const float* b_lift  = (const float*)d_in[4];
    const float* kW1     = (const float*)d_in[5];
    const float* kb1     = (const float*)d_in[6];
    const float* kW2     = (const float*)d_in[7];
    const float* kb2     = (const float*)d_in[8];
    const float* kW3     = (const float*)d_in[9];
    const float* kb3     = (const float*)d_in[10];
    float* out = (float*)d_out;

    float* f = (float*)d_ws;   // B*N*C fp32 = 512 KB scratch
    lift_kernel<<<(B_ * N_ + 7) / 8, 256, 0, stream>>>(pndata, W_lift, b_lift, f);
    magno_mfma<<<B_ * NL_, 128, 0, stream>>>(
        x_coord, lat, kW1, kb1, kW2, kb2, kW3, kb3, f, out);
}